// Round 14
// baseline (169.114 us; speedup 1.0000x reference)
//
#include <hip/hip_runtime.h>
#include <stdint.h>

#define M_TOK 512
#define N_OUT 11008
#define K_IN  4096
#define BM 128
#define BN 128
#define BK 64
#define KSPLIT_LEN 2048

typedef int i32x4 __attribute__((ext_vector_type(4)));

// =============================================================================
// Pre-pass: per-token-row int8 quantization of x (absmax/127), emitted in
// MFMA-FRAGMENT layout: chunk (kc16 = k>>4, gm = m>>4) stored at
//   x8f[((kc16*32) + gm)*256 + (m&15)*16 + (k&15)]
// A-frag load = fully coalesced dwordx4 from the L2-resident 2MB buffer.
// Verified rounds 11-13 (absmax 4.125).
// =============================================================================
__global__ void xquant_kernel(const float* __restrict__ x, int8_t* __restrict__ x8f,
                              float* __restrict__ sx) {
  const int row = blockIdx.x * 4 + (threadIdx.x >> 6);
  const int lane = threadIdx.x & 63;
  const float4* xr = (const float4*)(x + (size_t)row * K_IN);

  float4 v[16];
  float m = 0.f;
#pragma unroll
  for (int j = 0; j < 16; ++j) {
    v[j] = xr[lane * 16 + j];
    m = fmaxf(m, fmaxf(fmaxf(fabsf(v[j].x), fabsf(v[j].y)),
                       fmaxf(fabsf(v[j].z), fabsf(v[j].w))));
  }
#pragma unroll
  for (int o = 32; o; o >>= 1) m = fmaxf(m, __shfl_xor(m, o));

  const float inv = 127.0f / m;
  if (lane == 0) sx[row] = m / 127.0f;

  uint32_t d[16];
#pragma unroll
  for (int j = 0; j < 16; ++j) {
    int a = __float2int_rn(v[j].x * inv);
    int b = __float2int_rn(v[j].y * inv);
    int c = __float2int_rn(v[j].z * inv);
    int e = __float2int_rn(v[j].w * inv);
    d[j] = (a & 0xFF) | ((b & 0xFF) << 8) | ((c & 0xFF) << 16) | (e << 24);
  }
  const int gm = row >> 4, mr = row & 15;
#pragma unroll
  for (int q = 0; q < 4; ++q) {
    const int kc16 = lane * 4 + q;
    *(uint4*)&x8f[(size_t)(kc16 * 32 + gm) * 256 + mr * 16] =
        make_uint4(d[4 * q], d[4 * q + 1], d[4 * q + 2], d[4 * q + 3]);
  }
}

// =============================================================================
// int8 GEMM, BM128 x BN128 x BK64, split-K=2, grid 688. Round-12 core (best:
// 89.3us): depth-2 software pipeline, all-static register slots (br0/br1,
// aA/aB; rule #20), lgkm-only raw barriers (vmcnt loads fly across), A frags
// register-direct from L2-resident x8f.
// NEW: reduce pass folded into the epilogue via deterministic int32 combine:
//   per (nt,mt) tile, atomic ticket: arrival 0 writes int partial + releases
//   "done"; arrival 1 acquire-waits (bounded: partner already running), adds
//   the partial into its registers, applies sx*sw & bias, writes out.
//   Integer addition is order-independent -> bit-deterministic output.
// =============================================================================
template <bool SPLIT>
__global__ __launch_bounds__(256, 2)
void qgemm_i8(const int8_t* __restrict__ x8f, const float* __restrict__ sx,
              const int* __restrict__ qw, const float* __restrict__ scale,
              const float* __restrict__ bias, float* __restrict__ out,
              int* __restrict__ P, unsigned* __restrict__ cnt) {
  __shared__ __align__(16) int8_t Bs[2][BN * BK];  // 8KB each

  const int tid = threadIdx.x;
  const int lane = tid & 63;
  const int wid = tid >> 6;
  const int wm = wid >> 1, wn = wid & 1;
  const int kc = lane >> 4;

  int nt, mt, ks;
  if constexpr (SPLIT) {
    const int xcd = blockIdx.x & 7;
    const int g = xcd * 86 + (blockIdx.x >> 3);
    nt = g >> 3;
    const int r = g & 7;
    ks = r >> 2;
    mt = r & 3;
  } else {
    const int xcd = blockIdx.x & 7;
    const int g = xcd * 43 + (blockIdx.x >> 3);
    nt = g >> 2;
    mt = g & 3;
    ks = 0;
  }
  const int bm0 = mt * BM, bn0 = nt * BN;
  const int kbase = SPLIT ? ks * KSPLIT_LEN : 0;
  const int NIT = (SPLIT ? KSPLIT_LEN : K_IN) / BK;

  const int gmbase = (bm0 >> 4) + wm * 4;

  i32x4 acc[4][4] = {};
  i32x4 aA[4], aB[4];
  int4 br0[8], br1[8];

  const int brow = tid >> 2;
  const int bq = tid & 3;

#define LGKM_BAR() asm volatile("s_waitcnt lgkmcnt(0)\ns_barrier" ::: "memory")

#define A_FRAG_LOAD(DST, kb)                                                     \
  {                                                                              \
    const int kc16 = ((kb) >> 4) + kc;                                           \
    _Pragma("unroll") for (int mi = 0; mi < 4; ++mi) {                           \
      DST[mi] = *(const i32x4*)&x8f[(size_t)(kc16 * 32 + gmbase + mi) * 256 +    \
                                    (lane & 15) * 16];                           \
    }                                                                            \
  }

#define B_ISSUE(REG, kb)                                                         \
  {                                                                              \
    _Pragma("unroll") for (int j = 0; j < 2; ++j) {                              \
      const int row = brow + j * 64;                                             \
      const int4* bp = (const int4*)(qw + (size_t)(bn0 + row) * K_IN + (kb) + bq * 16); \
      _Pragma("unroll") for (int k = 0; k < 4; ++k) REG[4 * j + k] = bp[k];      \
    }                                                                            \
  }

#define B_WRITE(REG, BI)                                                         \
  {                                                                              \
    _Pragma("unroll") for (int j = 0; j < 2; ++j) {                              \
      const int row = brow + j * 64;                                             \
      uint32_t d[4];                                                             \
      _Pragma("unroll") for (int k = 0; k < 4; ++k) {                            \
        int4 w = REG[4 * j + k];                                                 \
        uint32_t lo = __builtin_amdgcn_perm((uint32_t)w.y, (uint32_t)w.x, 0x0C0C0400u); \
        uint32_t hi = __builtin_amdgcn_perm((uint32_t)w.w, (uint32_t)w.z, 0x04000C0Cu); \
        d[k] = lo | hi;                                                          \
      }                                                                          \
      const int ch = bq ^ ((row >> 1) & 3);                                      \
      *(uint4*)&Bs[BI][row * 64 + ch * 16] = make_uint4(d[0], d[1], d[2], d[3]); \
    }                                                                            \
  }

#define COMPUTE(AR, BI)                                                          \
  {                                                                              \
    i32x4 b[4];                                                                  \
    _Pragma("unroll") for (int ni = 0; ni < 4; ++ni) {                           \
      const int row = wn * 64 + ni * 16 + (lane & 15);                           \
      const int ch = kc ^ ((row >> 1) & 3);                                      \
      b[ni] = *(const i32x4*)&Bs[BI][row * 64 + ch * 16];                        \
    }                                                                            \
    __builtin_amdgcn_s_setprio(1);                                               \
    _Pragma("unroll") for (int mi = 0; mi < 4; ++mi)                             \
      _Pragma("unroll") for (int ni = 0; ni < 4; ++ni)                           \
        acc[mi][ni] = __builtin_amdgcn_mfma_i32_16x16x64_i8(AR[mi], b[ni],       \
                                                            acc[mi][ni], 0, 0, 0); \
    __builtin_amdgcn_s_setprio(0);                                               \
  }

  // ---- prologue: tiles 0,1 in flight; tile 0 staged ----
  B_ISSUE(br0, kbase);
  B_ISSUE(br1, kbase + BK);
  A_FRAG_LOAD(aA, kbase);
  A_FRAG_LOAD(aB, kbase + BK);
  B_WRITE(br0, 0);  // counted vmcnt wait on br0 only

#pragma unroll 1
  for (int t = 0; t < NIT; t += 2) {
    LGKM_BAR();
    if (t + 2 < NIT) B_ISSUE(br0, kbase + (t + 2) * BK);
    COMPUTE(aA, 0);
    if (t + 2 < NIT) A_FRAG_LOAD(aA, kbase + (t + 2) * BK);
    B_WRITE(br1, 1);

    LGKM_BAR();
    if (t + 3 < NIT) B_ISSUE(br1, kbase + (t + 3) * BK);
    COMPUTE(aB, 1);
    if (t + 3 < NIT) A_FRAG_LOAD(aB, kbase + (t + 3) * BK);
    if (t + 2 < NIT) B_WRITE(br0, 0);
  }

  // ---- split combine: deterministic int32 handoff ----
  if constexpr (SPLIT) {
    const int tile = nt * 4 + mt;
    int* Pt = P + (size_t)tile * (BM * BN);
    unsigned* cs = cnt + 2 * tile;  // [ticket, done]
    volatile int* flg = (volatile int*)&Bs[0][0];

    if (tid == 0) *flg = (int)atomicAdd(&cs[0], 1u);
    __syncthreads();
    const int role = *flg;

    if (role == 0) {
      // writer: store int partial, release-signal, exit
#pragma unroll
      for (int ni = 0; ni < 4; ++ni) {
        const int lc = wn * 64 + ni * 16 + (lane & 15);
#pragma unroll
        for (int mi = 0; mi < 4; ++mi) {
          const int lr0 = wm * 64 + mi * 16 + (lane >> 4) * 4;
#pragma unroll
          for (int r = 0; r < 4; ++r) Pt[(lr0 + r) * BN + lc] = acc[mi][ni][r];
        }
      }
      __syncthreads();  // all partial stores complete (vmcnt drained)
      if (tid == 0) {
        __threadfence();
        __hip_atomic_fetch_add(&cs[1], 1u, __ATOMIC_RELEASE, __HIP_MEMORY_SCOPE_AGENT);
      }
      return;
    }
    // combiner: bounded wait (writer ticketed strictly before us -> running)
    if (tid == 0) {
      while (__hip_atomic_load(&cs[1], __ATOMIC_ACQUIRE, __HIP_MEMORY_SCOPE_AGENT) == 0u)
        __builtin_amdgcn_s_sleep(8);
    }
    __syncthreads();
    __threadfence();
#pragma unroll
    for (int ni = 0; ni < 4; ++ni) {
      const int lc = wn * 64 + ni * 16 + (lane & 15);
#pragma unroll
      for (int mi = 0; mi < 4; ++mi) {
        const int lr0 = wm * 64 + mi * 16 + (lane >> 4) * 4;
#pragma unroll
        for (int r = 0; r < 4; ++r) acc[mi][ni][r] += Pt[(lr0 + r) * BN + lc];
      }
    }
  }

  // ---- float epilogue (combiner or non-split): out = acc*sx*sw + bias ----
  float sxr[4][4];
#pragma unroll
  for (int mi = 0; mi < 4; ++mi)
#pragma unroll
    for (int r = 0; r < 4; ++r)
      sxr[mi][r] = sx[bm0 + wm * 64 + mi * 16 + (lane >> 4) * 4 + r];

#pragma unroll
  for (int ni = 0; ni < 4; ++ni) {
    const int col = bn0 + wn * 64 + ni * 16 + (lane & 15);
    const float sw = scale[col];
    const float bi = bias[col];
#pragma unroll
    for (int mi = 0; mi < 4; ++mi) {
      const int rowb = bm0 + wm * 64 + mi * 16 + (lane >> 4) * 4;
#pragma unroll
      for (int r = 0; r < 4; ++r) {
        out[(size_t)(rowb + r) * N_OUT + col] = (float)acc[mi][ni][r] * sxr[mi][r] * sw + bi;
      }
    }
  }
#undef LGKM_BAR
#undef A_FRAG_LOAD
#undef B_ISSUE
#undef B_WRITE
#undef COMPUTE
}

// ---- naive fallback (ws too small; not expected to run) ---------------------
__global__ void qgemm_naive(const float* __restrict__ x, const int* __restrict__ qw,
                            const float* __restrict__ scale, const float* __restrict__ bias,
                            float* __restrict__ out) {
  int o = blockIdx.x * blockDim.x + threadIdx.x;
  if (o >= M_TOK * N_OUT) return;
  int row = o / N_OUT, col = o % N_OUT;
  const float* xr = x + (size_t)row * K_IN;
  const int* wr = qw + (size_t)col * K_IN;
  float acc = 0.f;
  for (int k = 0; k < K_IN; ++k) acc += xr[k] * (float)wr[k];
  out[o] = acc * scale[col] + bias[col];
}

// ---- launch ------------------------------------------------------------------
extern "C" void kernel_launch(void* const* d_in, const int* in_sizes, int n_in,
                              void* d_out, int out_size, void* d_ws, size_t ws_size,
                              hipStream_t stream) {
  const float* x = (const float*)d_in[0];
  const int* qw = (const int*)d_in[1];
  const float* scale = (const float*)d_in[2];
  const float* bias = (const float*)d_in[3];
  float* out = (float*)d_out;

  const size_t sx_bytes = 4096;                              // 512 floats, padded
  const size_t x8_bytes = (size_t)M_TOK * K_IN;              // 2 MB
  const size_t P_bytes = (size_t)344 * BM * BN * 4;          // 22.0 MB int partials
  const size_t cnt_bytes = 344 * 2 * sizeof(unsigned);       // 2752 B

  if (ws_size >= sx_bytes + x8_bytes + P_bytes + cnt_bytes) {
    float* sx = (float*)d_ws;
    int8_t* x8f = (int8_t*)((char*)d_ws + sx_bytes);
    int* P = (int*)((char*)d_ws + sx_bytes + x8_bytes);
    unsigned* cnt = (unsigned*)((char*)d_ws + sx_bytes + x8_bytes + P_bytes);
    hipMemsetAsync(cnt, 0, cnt_bytes, stream);
    xquant_kernel<<<dim3(M_TOK / 4), dim3(256), 0, stream>>>(x, x8f, sx);
    qgemm_i8<true><<<dim3(688), dim3(256), 0, stream>>>(x8f, sx, qw, scale, bias, out, P, cnt);
  } else if (ws_size >= sx_bytes + x8_bytes) {
    float* sx = (float*)d_ws;
    int8_t* x8f = (int8_t*)((char*)d_ws + sx_bytes);
    xquant_kernel<<<dim3(M_TOK / 4), dim3(256), 0, stream>>>(x, x8f, sx);
    qgemm_i8<false><<<dim3(344), dim3(256), 0, stream>>>(x8f, sx, qw, scale, bias, out,
                                                         nullptr, nullptr);
  } else {
    qgemm_naive<<<dim3((M_TOK * N_OUT + 255) / 256), dim3(256), 0, stream>>>(
        x, qw, scale, bias, out);
  }
}

// Round 15
// 80.470 us; speedup vs baseline: 2.1016x; 2.1016x over previous
//
#include <hip/hip_runtime.h>
#include <stdint.h>

#define M_TOK 512
#define N_OUT 11008
#define K_IN  4096
#define BM 256
#define BN 128
#define BK 64
#define KSPLIT_LEN 2048

typedef int i32x4 __attribute__((ext_vector_type(4)));

// =============================================================================
// Pre-pass: per-token-row int8 quantization of x (absmax/127), emitted in
// MFMA-FRAGMENT layout: chunk (kc16 = k>>4, gm = m>>4) stored at
//   x8f[((kc16*32) + gm)*256 + (m&15)*16 + (k&15)]
// A-frag load = fully coalesced dwordx4 from the L2-resident 2MB buffer.
// Verified rounds 11-14 (absmax 4.125).
// =============================================================================
__global__ void xquant_kernel(const float* __restrict__ x, int8_t* __restrict__ x8f,
                              float* __restrict__ sx) {
  const int row = blockIdx.x * 4 + (threadIdx.x >> 6);
  const int lane = threadIdx.x & 63;
  const float4* xr = (const float4*)(x + (size_t)row * K_IN);

  float4 v[16];
  float m = 0.f;
#pragma unroll
  for (int j = 0; j < 16; ++j) {
    v[j] = xr[lane * 16 + j];
    m = fmaxf(m, fmaxf(fmaxf(fabsf(v[j].x), fabsf(v[j].y)),
                       fmaxf(fabsf(v[j].z), fabsf(v[j].w))));
  }
#pragma unroll
  for (int o = 32; o; o >>= 1) m = fmaxf(m, __shfl_xor(m, o));

  const float inv = 127.0f / m;
  if (lane == 0) sx[row] = m / 127.0f;

  uint32_t d[16];
#pragma unroll
  for (int j = 0; j < 16; ++j) {
    int a = __float2int_rn(v[j].x * inv);
    int b = __float2int_rn(v[j].y * inv);
    int c = __float2int_rn(v[j].z * inv);
    int e = __float2int_rn(v[j].w * inv);
    d[j] = (a & 0xFF) | ((b & 0xFF) << 8) | ((c & 0xFF) << 16) | (e << 24);
  }
  const int gm = row >> 4, mr = row & 15;
#pragma unroll
  for (int q = 0; q < 4; ++q) {
    const int kc16 = lane * 4 + q;
    *(uint4*)&x8f[(size_t)(kc16 * 32 + gm) * 256 + mr * 16] =
        make_uint4(d[4 * q], d[4 * q + 1], d[4 * q + 2], d[4 * q + 3]);
  }
}

// ---- reduce: out += part ----------------------------------------------------
__global__ void reduce_kernel(float4* __restrict__ out, const float4* __restrict__ p, int n4) {
  int i = blockIdx.x * blockDim.x + threadIdx.x;
  int stride = gridDim.x * blockDim.x;
  for (; i < n4; i += stride) {
    float4 a = out[i];
    float4 b = p[i];
    a.x += b.x; a.y += b.y; a.z += b.z; a.w += b.w;
    out[i] = a;
  }
}

// =============================================================================
// int8 GEMM, BM256 x BN128 x BK64, split-K=2, grid 344 x 512 threads.
// 8 waves = 4wm x 2wn; each wave the round-12 64x64 tile (acc[4][4]).
// TA-byte halving vs round 12: W passes M/BM = 2 (was 4) -> B TA 360 MB;
// per-thread staging halves (B: 4 dwordx4 + 1 ds_write_b128).
// Depth-1 prefetch (round-9 order) to fit VGPR<=128 (2 blocks/CU):
//   bar -> B_ISSUE(t+1) -> COMPUTE(t) -> A_FRAG_LOAD(t+1) -> B_WRITE(t+1).
// lgkm-only raw barriers: global loads fly across (compiler counted-waits).
// =============================================================================
template <bool SPLIT>
__global__ __launch_bounds__(512, 4)
void qgemm_i8(const int8_t* __restrict__ x8f, const float* __restrict__ sx,
              const int* __restrict__ qw, const float* __restrict__ scale,
              const float* __restrict__ bias, float* __restrict__ out,
              float* __restrict__ part) {
  __shared__ __align__(16) int8_t Bs[2][BN * BK];  // 8KB each (16KB total)

  const int tid = threadIdx.x;
  const int lane = tid & 63;
  const int wid = tid >> 6;           // 0..7
  const int wm = wid >> 1, wn = wid & 1;  // wm 0..3, wn 0..1
  const int kc = lane >> 4;

  int nt, mt, ks;
  if constexpr (SPLIT) {
    // grid 344 = 8*43: 4 consecutive g = one W panel (2 mt x 2 ks) per XCD
    const int xcd = blockIdx.x & 7;
    const int g = xcd * 43 + (blockIdx.x >> 3);
    nt = g >> 2;
    const int r = g & 3;
    ks = r >> 1;
    mt = r & 1;
  } else {
    nt = blockIdx.x >> 1;
    mt = blockIdx.x & 1;
    ks = 0;
  }
  const int bm0 = mt * BM, bn0 = nt * BN;
  const int kbase = SPLIT ? ks * KSPLIT_LEN : 0;
  const int NIT = (SPLIT ? KSPLIT_LEN : K_IN) / BK;

  const int gmbase = (bm0 >> 4) + wm * 4;

  i32x4 acc[4][4] = {};
  i32x4 aA[4];
  int4 br[4];  // depth-1: 4 dwordx4 = 64B of one W row

  const int brow = tid >> 2;  // 0..127
  const int bq = tid & 3;     // 64B quad within the 256B row span

#define LGKM_BAR() asm volatile("s_waitcnt lgkmcnt(0)\ns_barrier" ::: "memory")

#define A_FRAG_LOAD(kb)                                                          \
  {                                                                              \
    const int kc16 = ((kb) >> 4) + kc;                                           \
    _Pragma("unroll") for (int mi = 0; mi < 4; ++mi) {                           \
      aA[mi] = *(const i32x4*)&x8f[(size_t)(kc16 * 32 + gmbase + mi) * 256 +     \
                                   (lane & 15) * 16];                            \
    }                                                                            \
  }

#define B_ISSUE(kb)                                                              \
  {                                                                              \
    const int4* bp = (const int4*)(qw + (size_t)(bn0 + brow) * K_IN + (kb) + bq * 16); \
    _Pragma("unroll") for (int k = 0; k < 4; ++k) br[k] = bp[k];                 \
  }

#define B_WRITE(BI)                                                              \
  {                                                                              \
    uint32_t d[4];                                                               \
    _Pragma("unroll") for (int k = 0; k < 4; ++k) {                              \
      int4 w = br[k];                                                            \
      uint32_t lo = __builtin_amdgcn_perm((uint32_t)w.y, (uint32_t)w.x, 0x0C0C0400u); \
      uint32_t hi = __builtin_amdgcn_perm((uint32_t)w.w, (uint32_t)w.z, 0x04000C0Cu); \
      d[k] = lo | hi;                                                            \
    }                                                                            \
    const int ch = bq ^ ((brow >> 1) & 3);                                       \
    *(uint4*)&Bs[BI][brow * 64 + ch * 16] = make_uint4(d[0], d[1], d[2], d[3]);  \
  }

#define COMPUTE(BI)                                                              \
  {                                                                              \
    i32x4 b[4];                                                                  \
    _Pragma("unroll") for (int ni = 0; ni < 4; ++ni) {                           \
      const int row = wn * 64 + ni * 16 + (lane & 15);                           \
      const int ch = kc ^ ((row >> 1) & 3);                                      \
      b[ni] = *(const i32x4*)&Bs[BI][row * 64 + ch * 16];                        \
    }                                                                            \
    __builtin_amdgcn_s_setprio(1);                                               \
    _Pragma("unroll") for (int mi = 0; mi < 4; ++mi)                             \
      _Pragma("unroll") for (int ni = 0; ni < 4; ++ni)                           \
        acc[mi][ni] = __builtin_amdgcn_mfma_i32_16x16x64_i8(aA[mi], b[ni],       \
                                                            acc[mi][ni], 0, 0, 0); \
    __builtin_amdgcn_s_setprio(0);                                               \
  }

  // ---- prologue: tile 0 staged, A(0) in regs ----
  B_ISSUE(kbase);
  A_FRAG_LOAD(kbase);
  B_WRITE(0);  // auto counted-vmcnt wait on br only

#pragma unroll 1
  for (int t = 0; t < NIT; ++t) {
    const int cur = t & 1;
    LGKM_BAR();  // Bs[cur] writes visible; WAR on Bs[cur^1]

    if (t + 1 < NIT) B_ISSUE(kbase + (t + 1) * BK);  // L2/L3 latency under compute
    COMPUTE(cur);
    if (t + 1 < NIT) {
      A_FRAG_LOAD(kbase + (t + 1) * BK);  // L2-hot; ~1 iter of cover
      B_WRITE(cur ^ 1);                   // br landed during compute
    }
  }

  // ---- epilogue: out = acc * sx[row] * sw[col] (+ bias on ks==0) ----
  float* dst = out;
  float badd = 1.0f;
  if constexpr (SPLIT) {
    if (ks == 1) { dst = part; badd = 0.0f; }
  }
  float sxr[4][4];
#pragma unroll
  for (int mi = 0; mi < 4; ++mi)
#pragma unroll
    for (int r = 0; r < 4; ++r)
      sxr[mi][r] = sx[bm0 + wm * 64 + mi * 16 + (lane >> 4) * 4 + r];

#pragma unroll
  for (int ni = 0; ni < 4; ++ni) {
    const int col = bn0 + wn * 64 + ni * 16 + (lane & 15);
    const float sw = scale[col];
    const float bi = bias[col] * badd;
#pragma unroll
    for (int mi = 0; mi < 4; ++mi) {
      const int rowb = bm0 + wm * 64 + mi * 16 + (lane >> 4) * 4;
#pragma unroll
      for (int r = 0; r < 4; ++r) {
        dst[(size_t)(rowb + r) * N_OUT + col] = (float)acc[mi][ni][r] * sxr[mi][r] * sw + bi;
      }
    }
  }
#undef LGKM_BAR
#undef A_FRAG_LOAD
#undef B_ISSUE
#undef B_WRITE
#undef COMPUTE
}

// ---- naive fallback (ws too small; not expected to run) ---------------------
__global__ void qgemm_naive(const float* __restrict__ x, const int* __restrict__ qw,
                            const float* __restrict__ scale, const float* __restrict__ bias,
                            float* __restrict__ out) {
  int o = blockIdx.x * blockDim.x + threadIdx.x;
  if (o >= M_TOK * N_OUT) return;
  int row = o / N_OUT, col = o % N_OUT;
  const float* xr = x + (size_t)row * K_IN;
  const int* wr = qw + (size_t)col * K_IN;
  float acc = 0.f;
  for (int k = 0; k < K_IN; ++k) acc += xr[k] * (float)wr[k];
  out[o] = acc * scale[col] + bias[col];
}

// ---- launch ------------------------------------------------------------------
extern "C" void kernel_launch(void* const* d_in, const int* in_sizes, int n_in,
                              void* d_out, int out_size, void* d_ws, size_t ws_size,
                              hipStream_t stream) {
  const float* x = (const float*)d_in[0];
  const int* qw = (const int*)d_in[1];
  const float* scale = (const float*)d_in[2];
  const float* bias = (const float*)d_in[3];
  float* out = (float*)d_out;

  const size_t sx_bytes = 4096;                         // 512 floats, padded
  const size_t x8_bytes = (size_t)M_TOK * K_IN;         // 2 MB
  const size_t part_bytes = (size_t)M_TOK * N_OUT * 4;  // 22.5 MB
  const int n4 = M_TOK * N_OUT / 4;

  if (ws_size >= sx_bytes + x8_bytes + part_bytes) {
    float* sx = (float*)d_ws;
    int8_t* x8f = (int8_t*)((char*)d_ws + sx_bytes);
    float* part = (float*)((char*)d_ws + sx_bytes + x8_bytes);
    xquant_kernel<<<dim3(M_TOK / 4), dim3(256), 0, stream>>>(x, x8f, sx);
    qgemm_i8<true><<<dim3(344), dim3(512), 0, stream>>>(x8f, sx, qw, scale, bias, out, part);
    reduce_kernel<<<dim3(2048), dim3(256), 0, stream>>>((float4*)out, (const float4*)part, n4);
  } else if (ws_size >= sx_bytes + x8_bytes) {
    float* sx = (float*)d_ws;
    int8_t* x8f = (int8_t*)((char*)d_ws + sx_bytes);
    xquant_kernel<<<dim3(M_TOK / 4), dim3(256), 0, stream>>>(x, x8f, sx);
    qgemm_i8<false><<<dim3(172), dim3(512), 0, stream>>>(x8f, sx, qw, scale, bias, out, nullptr);
  } else {
    qgemm_naive<<<dim3((M_TOK * N_OUT + 255) / 256), dim3(256), 0, stream>>>(
        x, qw, scale, bias, out);
  }
}